// Round 11
// baseline (359.234 us; speedup 1.0000x reference)
//
#include <hip/hip_runtime.h>
#include <hip/hip_bf16.h>

typedef __attribute__((ext_vector_type(8))) short short8;
typedef __attribute__((ext_vector_type(4))) float f32x4;
typedef __attribute__((ext_vector_type(16))) float f32x16;

#define SEQ 2048
#define DIM 3072
#define NHEAD 24
#define HDIM 128
#define SCALE_Q 0.12751744f  // (1/sqrt(128)) * log2(e)

__device__ __forceinline__ unsigned short f2bf(float f) {
  unsigned int b = __float_as_uint(f);
  b += 0x7fffu + ((b >> 16) & 1u);
  return (unsigned short)(b >> 16);
}
__device__ __forceinline__ float bf2f(unsigned short u) {
  return __uint_as_float(((unsigned int)u) << 16);
}
__device__ __forceinline__ unsigned int pkbf(float a, float b) {
  __hip_bfloat162 h = __float22bfloat162_rn(make_float2(a, b));
  return *(unsigned int*)&h;
}

__device__ __forceinline__ void async16(const void* g, void* l) {
  __builtin_amdgcn_global_load_lds(
      (const __attribute__((address_space(1))) unsigned int*)g,
      (__attribute__((address_space(3))) unsigned int*)l, 16, 0, 0);
}

// ---------------- cast x (fp32 -> bf16), 8 elems/thread ----------------
__global__ void k_cvt_x(const float* __restrict__ x, unsigned short* __restrict__ xb) {
  int idx = (blockIdx.x * 256 + threadIdx.x) * 8;
  float4 a = *(const float4*)(x + idx);
  float4 b = *(const float4*)(x + idx + 4);
  short8 o;
  o[0] = (short)f2bf(a.x); o[1] = (short)f2bf(a.y);
  o[2] = (short)f2bf(a.z); o[3] = (short)f2bf(a.w);
  o[4] = (short)f2bf(b.x); o[5] = (short)f2bf(b.y);
  o[6] = (short)f2bf(b.z); o[7] = (short)f2bf(b.w);
  *(short8*)(xb + idx) = o;
}

// ---------------- transpose + cast one W (K x N fp32) -> Wt rows (N x K bf16) ----------------
__device__ __forceinline__ void transpose_tile(const float* __restrict__ w,
                                               unsigned short* __restrict__ wt,
                                               int n0, int k0, int outRowBase, int t) {
  __shared__ unsigned short tile[64][68];
  int c4 = (t & 15) * 4;
  int r0 = t >> 4;
#pragma unroll
  for (int j = 0; j < 4; ++j) {
    int r = r0 + 16 * j;
    float4 v = *(const float4*)(w + (size_t)(k0 + r) * DIM + n0 + c4);
    ushort4 u;
    u.x = f2bf(v.x); u.y = f2bf(v.y); u.z = f2bf(v.z); u.w = f2bf(v.w);
    *(ushort4*)&tile[r][c4] = u;
  }
  __syncthreads();
#pragma unroll
  for (int j = 0; j < 4; ++j) {
    int nn = r0 + 16 * j;
    ushort4 u;
    u.x = tile[c4 + 0][nn]; u.y = tile[c4 + 1][nn];
    u.z = tile[c4 + 2][nn]; u.w = tile[c4 + 3][nn];
    *(ushort4*)(wt + (size_t)(outRowBase + n0 + nn) * DIM + k0 + c4) = u;
  }
}

__global__ __launch_bounds__(256) void k_transpose(const float* __restrict__ w,
                                                   unsigned short* __restrict__ wt) {
  transpose_tile(w, wt, blockIdx.x * 64, blockIdx.y * 64, 0, threadIdx.x);
}

__global__ __launch_bounds__(256) void k_transpose3(const float* __restrict__ w0,
                                                    const float* __restrict__ w1,
                                                    const float* __restrict__ w2,
                                                    unsigned short* __restrict__ wt) {
  const float* w = blockIdx.z == 0 ? w0 : (blockIdx.z == 1 ? w1 : w2);
  transpose_tile(w, wt, blockIdx.x * 64, blockIdx.y * 64, blockIdx.z * DIM, threadIdx.x);
}

// ---------------- fallback GEMM core: one 128x128 tile, BK=64, T2 swizzle ----------------
__device__ __forceinline__ void gemm_tile(const unsigned short* __restrict__ xb,
                                          const unsigned short* __restrict__ wt,
                                          int bm, int bn, int t, f32x4 (&acc)[4][4],
                                          unsigned short* As, unsigned short* Bs) {
  int l = t & 63, w = t >> 6;
  int wr = w >> 1, wc = w & 1;
  int lr = l & 15, kc = l >> 4;
  const char* aB = (const char*)xb;
  const char* bB = (const char*)wt;
  char* asmB = (char*)As;
  char* bsmB = (char*)Bs;
  int sw = (lr & 7) << 4;

  for (int k0 = 0; k0 < DIM; k0 += 64) {
#pragma unroll
    for (int i = 0; i < 4; ++i) {
      int off = (t + 256 * i) * 16;
      int row = off >> 7;
      int cb = off & 127;
      int scb = cb ^ ((row & 7) << 4);
      async16(aB + ((size_t)(bm * 128 + row) * DIM + k0) * 2 + scb, asmB + off);
      async16(bB + ((size_t)(bn * 128 + row) * DIM + k0) * 2 + scb, bsmB + off);
    }
    __syncthreads();
#pragma unroll
    for (int kk = 0; kk < 2; ++kk) {
      short8 af[4], bf[4];
#pragma unroll
      for (int m = 0; m < 4; ++m)
        af[m] = *(const short8*)(asmB + (wr * 64 + m * 16 + lr) * 128 +
                                 ((kk * 64 + kc * 16) ^ sw));
#pragma unroll
      for (int n = 0; n < 4; ++n)
        bf[n] = *(const short8*)(bsmB + (wc * 64 + n * 16 + lr) * 128 +
                                 ((kk * 64 + kc * 16) ^ sw));
#pragma unroll
      for (int m = 0; m < 4; ++m)
#pragma unroll
        for (int n = 0; n < 4; ++n)
          acc[m][n] = __builtin_amdgcn_mfma_f32_16x16x32_bf16(af[m], bf[n], acc[m][n], 0, 0, 0);
    }
    __syncthreads();
  }
}

// ---------------- fallback GEMM (one W at a time) ----------------
__global__ __launch_bounds__(256) void k_gemm(const unsigned short* __restrict__ xb,
                                              const unsigned short* __restrict__ wt,
                                              const float* __restrict__ bias,
                                              unsigned short* __restrict__ out,
                                              int vmode) {
  __shared__ unsigned short As[128 * 64];
  __shared__ unsigned short Bs[128 * 64];
  int t = threadIdx.x;
  int fid = blockIdx.x;
  int logical = (fid & 7) * 48 + (fid >> 3);
  int bm = logical & 15, bn = logical >> 4;

  f32x4 acc[4][4];
#pragma unroll
  for (int m = 0; m < 4; ++m)
#pragma unroll
    for (int n = 0; n < 4; ++n) acc[m][n] = (f32x4){0.f, 0.f, 0.f, 0.f};

  gemm_tile(xb, wt, bm, bn, t, acc, As, Bs);

  int l = t & 63, w = t >> 6;
  int wr = w >> 1, wc = w & 1;
  int lr = l & 15, lq = l >> 4;
  if (vmode) {
#pragma unroll
    for (int m = 0; m < 4; ++m)
#pragma unroll
      for (int n = 0; n < 4; ++n) {
        int gcol = bn * 128 + wc * 64 + n * 16 + lr;
        float bv = bias[gcol];
        int grow = bm * 128 + wr * 64 + m * 16 + lq * 4;
        ushort4 u;
        u.x = f2bf(acc[m][n][0] + bv);
        u.y = f2bf(acc[m][n][1] + bv);
        u.z = f2bf(acc[m][n][2] + bv);
        u.w = f2bf(acc[m][n][3] + bv);
        *(ushort4*)(out + (size_t)gcol * SEQ + grow) = u;
      }
  } else {
#pragma unroll
    for (int m = 0; m < 4; ++m)
#pragma unroll
      for (int n = 0; n < 4; ++n) {
        int gcol = bn * 128 + wc * 64 + n * 16 + lr;
        float bv = bias[gcol];
#pragma unroll
        for (int i = 0; i < 4; ++i) {
          int grow = bm * 128 + wr * 64 + m * 16 + lq * 4 + i;
          out[(size_t)grow * DIM + gcol] = f2bf(acc[m][n][i] + bv);
        }
      }
  }
}

// ---------------- 8-phase-style fused GEMM: BM=128, BN=256, BK=32, 3 rolling bufs ----
// 512 threads = 8 waves (2x4), per-wave 64x64 output. Per K-tile phase:
// {8 ds_read || 3 global_load_lds(kt+2) -> vmcnt(3) -> s_barrier -> 16 MFMA -> s_barrier}.
// Loads stay in flight ~2 phases; vmcnt never drained to 0 inside the loop (T4).
// Fused bias + RMSNorm + RoPE epilogue (BN=256 = 2 heads).
__global__ __launch_bounds__(512, 2) void k_gemm8(
    const unsigned short* __restrict__ xb, const unsigned short* __restrict__ wt,
    const float* __restrict__ bq, const float* __restrict__ bk,
    const float* __restrict__ bv, const float* __restrict__ rope_cos,
    const float* __restrict__ rope_sin, const float* __restrict__ gq,
    const float* __restrict__ gk, unsigned short* __restrict__ qb,
    unsigned short* __restrict__ kb, unsigned short* __restrict__ vtb) {
  __shared__ unsigned short As[3][128 * 32];  // 24 KB
  __shared__ unsigned short Bs[3][256 * 32];  // 48 KB
  __shared__ float ssum[4][128];
  const int t = threadIdx.x;  // 0..511
  const int l = t & 63, w = t >> 6;
  const int wm = w >> 2, wn = w & 3;  // 2 x 4 wave grid
  const int lr = l & 15, lq = l >> 4;
  int fid = blockIdx.x;
  int g = (fid & 7) * 72 + (fid >> 3);  // bijective 576 = 8 xcd * 72
  int bn = g >> 4, bm = g & 15;         // bn 0..35 (256-col tiles), bm 0..15
  const int sw3 = (lr & 3) << 4;

  // staging offsets (64 B rows, pre-swizzled source, linear LDS dest)
  int adst, asrc;
  {
    int off = t * 16;
    int row = off >> 6, cb = off & 63;
    adst = off;
    asrc = row * (DIM * 2) + (cb ^ ((row & 3) << 4));
  }
  int bdst0, bsrc0, bdst1, bsrc1;
  {
    int off = t * 16;
    int row = off >> 6, cb = off & 63;
    bdst0 = off;
    bsrc0 = row * (DIM * 2) + (cb ^ ((row & 3) << 4));
  }
  {
    int off = (t + 512) * 16;
    int row = off >> 6, cb = off & 63;
    bdst1 = off;
    bsrc1 = row * (DIM * 2) + (cb ^ ((row & 3) << 4));
  }

  const char* aB = (const char*)xb + (size_t)bm * 128 * (DIM * 2);
  const char* bB = (const char*)wt + (size_t)bn * 256 * (DIM * 2);

  f32x4 acc[4][4];
#pragma unroll
  for (int m = 0; m < 4; ++m)
#pragma unroll
    for (int n = 0; n < 4; ++n) acc[m][n] = (f32x4){0.f, 0.f, 0.f, 0.f};

  auto stage = [&](int kt, int b) {
    int kcol = kt * 64;  // BK=32 -> 64 bytes per K-step
    async16(aB + asrc + kcol, (char*)As[b] + adst);
    async16(bB + bsrc0 + kcol, (char*)Bs[b] + bdst0);
    async16(bB + bsrc1 + kcol, (char*)Bs[b] + bdst1);
  };

  // prologue: kt 0 -> buf0, kt 1 -> buf1; wait for kt0 only (kt1 stays in flight)
  stage(0, 0);
  stage(1, 1);
  asm volatile("s_waitcnt vmcnt(3)");
  __builtin_amdgcn_s_barrier();
  __builtin_amdgcn_sched_barrier(0);

  auto step = [&](int kt, int b, int bstage) {
    short8 af[4], bf[4];
    const char* Ab = (const char*)As[b];
    const char* Bb = (const char*)Bs[b];
    int colb = (lq * 16) ^ sw3;
#pragma unroll
    for (int mf = 0; mf < 4; ++mf)
      af[mf] = *(const short8*)(Ab + (wm * 64 + mf * 16 + lr) * 64 + colb);
#pragma unroll
    for (int nf = 0; nf < 4; ++nf)
      bf[nf] = *(const short8*)(Bb + (wn * 64 + nf * 16 + lr) * 64 + colb);
    if (kt + 2 < 96) {
      stage(kt + 2, bstage);
      asm volatile("s_waitcnt vmcnt(3)");  // wait kt+1's loads; kt+2's stay in flight
    } else {
      asm volatile("s_waitcnt vmcnt(0)");  // tail: drain
    }
    __builtin_amdgcn_s_barrier();
    __builtin_amdgcn_sched_barrier(0);
    __builtin_amdgcn_s_setprio(1);
#pragma unroll
    for (int mf = 0; mf < 4; ++mf)
#pragma unroll
      for (int nf = 0; nf < 4; ++nf)
        acc[mf][nf] =
            __builtin_amdgcn_mfma_f32_16x16x32_bf16(af[mf], bf[nf], acc[mf][nf], 0, 0, 0);
    __builtin_amdgcn_s_setprio(0);
    __builtin_amdgcn_s_barrier();
    __builtin_amdgcn_sched_barrier(0);
  };

  for (int ko = 0; ko < 96; ko += 3) {  // 96 K-tiles of 32
    step(ko + 0, 0, 2);
    step(ko + 1, 1, 0);
    step(ko + 2, 2, 1);
  }

  // ---------------- epilogue ----------------
  int region = bn / 12;     // 0=q, 1=k, 2=v
  int bnl = bn % 12;
  const float* bias = region == 0 ? bq : (region == 1 ? bk : bv);

  if (region == 2) {  // V: transposed write vtb[col][s]
#pragma unroll
    for (int m = 0; m < 4; ++m)
#pragma unroll
      for (int nf = 0; nf < 4; ++nf) {
        int gcol = bnl * 256 + wn * 64 + nf * 16 + lr;
        float bv_ = bias[gcol];
        int grow = bm * 128 + wm * 64 + m * 16 + lq * 4;
        ushort4 u;
        u.x = f2bf(acc[m][nf][0] + bv_);
        u.y = f2bf(acc[m][nf][1] + bv_);
        u.z = f2bf(acc[m][nf][2] + bv_);
        u.w = f2bf(acc[m][nf][3] + bv_);
        *(ushort4*)(vtb + (size_t)gcol * SEQ + grow) = u;
      }
  } else {  // q/k: fused bias + RMSNorm + RoPE
    unsigned short* outp = region == 0 ? qb : kb;
    const float* gg = region == 0 ? gq : gk;
    float scale = region == 0 ? SCALE_Q : 1.0f;
    int head = bnl * 2 + (wn >> 1);

    float gv[4], bvv[4];
    int colh[4];
#pragma unroll
    for (int nf = 0; nf < 4; ++nf) {
      colh[nf] = (wn & 1) * 64 + nf * 16 + lr;
      gv[nf] = gg[colh[nf]];
      bvv[nf] = bias[head * 128 + colh[nf]];
    }
#pragma unroll
    for (int m = 0; m < 4; ++m)
#pragma unroll
      for (int nf = 0; nf < 4; ++nf)
#pragma unroll
        for (int i = 0; i < 4; ++i) acc[m][nf][i] += bvv[nf];

    // per-row sum of squares: this wave's 64 cols, then cross-wave-pair via LDS
#pragma unroll
    for (int m = 0; m < 4; ++m)
#pragma unroll
      for (int i = 0; i < 4; ++i) {
        float ss = acc[m][0][i] * acc[m][0][i] + acc[m][1][i] * acc[m][1][i] +
                   acc[m][2][i] * acc[m][2][i] + acc[m][3][i] * acc[m][3][i];
        ss += __shfl_xor(ss, 1);
        ss += __shfl_xor(ss, 2);
        ss += __shfl_xor(ss, 4);
        ss += __shfl_xor(ss, 8);
        if (lr == m * 4 + i) ssum[wn][wm * 64 + m * 16 + lq * 4 + i] = ss;
      }
    __syncthreads();

    int p = (wn >> 1) * 2;
#pragma unroll
    for (int m = 0; m < 4; ++m)
#pragma unroll
      for (int i = 0; i < 4; ++i) {
        int rl = wm * 64 + m * 16 + lq * 4 + i;
        float rn = rsqrtf((ssum[p][rl] + ssum[p + 1][rl]) * (1.0f / 128.0f) + 1e-6f);
        int s_idx = bm * 128 + rl;
        const float* cr = rope_cos + (size_t)s_idx * HDIM;
        const float* sr = rope_sin + (size_t)s_idx * HDIM;
        unsigned short* orow = outp + (size_t)s_idx * DIM + head * 128;
#pragma unroll
        for (int nf = 0; nf < 4; ++nf) {
          int cl = colh[nf];
          float xn = acc[m][nf][i] * rn * gv[nf];
          float pr = __shfl_xor(xn, 1);
          float cv = cr[cl], sv = sr[cl];
          float o = (lr & 1) ? fmaf(xn, cv, pr * sv) : fmaf(xn, cv, -pr * sv);
          orow[cl] = f2bf(o * scale);
        }
      }
  }
}

// ---------------- RMSNorm + RoPE (fallback path only) ----------------
__global__ void k_normrope(unsigned short* __restrict__ qk, const float* __restrict__ cosb,
                           const float* __restrict__ sinb, const float* __restrict__ g,
                           float scale) {
  int t = threadIdx.x;
  int w = t >> 6, l = t & 63;
  int row = blockIdx.x * 4 + w;
  int s_idx = row / NHEAD, head = row % NHEAD;
  size_t base = (size_t)s_idx * DIM + head * HDIM;
  unsigned int pair = *(const unsigned int*)(qk + base + 2 * l);
  float x0 = bf2f((unsigned short)(pair & 0xffffu));
  float x1 = bf2f((unsigned short)(pair >> 16));
  float ss = x0 * x0 + x1 * x1;
#pragma unroll
  for (int off = 1; off < 64; off <<= 1) ss += __shfl_xor(ss, off);
  float r = rsqrtf(ss * (1.0f / 128.0f) + 1e-6f);
  float g0 = g[2 * l], g1 = g[2 * l + 1];
  float c0 = cosb[s_idx * HDIM + 2 * l], c1 = cosb[s_idx * HDIM + 2 * l + 1];
  float s0 = sinb[s_idx * HDIM + 2 * l], s1 = sinb[s_idx * HDIM + 2 * l + 1];
  float xn0 = x0 * r * g0, xn1 = x1 * r * g1;
  float o0 = (xn0 * c0 - xn1 * s0) * scale;
  float o1 = (xn1 * c1 + xn0 * s1) * scale;
  unsigned int po = (unsigned int)f2bf(o0) | ((unsigned int)f2bf(o1) << 16);
  *(unsigned int*)(qk + base + 2 * l) = po;
}

// ---------------- Flash attention: 4 waves x 32 q-rows, 2-phase dbuf (round-10) ----
__global__ __launch_bounds__(256, 2) void k_attn(const unsigned short* __restrict__ q,
                                                 const unsigned short* __restrict__ k,
                                                 const unsigned short* __restrict__ vt,
                                                 float* __restrict__ out) {
  __shared__ unsigned short Ksm[2][64 * 128];
  __shared__ unsigned short Vtsm[2][128 * 64];
  int t = threadIdx.x;
  int w = t >> 6, l = t & 63;
  int q32 = l & 31, hi = l >> 5;
  int hi4 = hi * 4;
  int fid = blockIdx.x;
  int logical = (fid & 7) * 48 + (fid >> 3);  // bijective: 384 = 8*48
  int qt = logical & 15, h = logical >> 4;
  int q0w = qt * 128 + w * 32;

  const char* kbase = (const char*)k + (size_t)h * HDIM * 2;
  const char* vbase = (const char*)vt + (size_t)h * HDIM * SEQ * 2;

  int koff[4], voff[4], dst[4];
#pragma unroll
  for (int i = 0; i < 4; ++i) {
    int off = (t + 256 * i) * 16;
    dst[i] = off;
    int krow = off >> 8, kcb = off & 255;
    koff[i] = krow * (DIM * 2) + (kcb ^ ((krow & 15) << 4));
    int vrow = off >> 7, vcb = off & 127;
    voff[i] = vrow * (SEQ * 2) + (vcb ^ ((vrow & 7) << 4));
  }

  short8 qf[8];
  {
    const unsigned short* qrow = q + (size_t)(q0w + q32) * DIM + h * HDIM;
#pragma unroll
    for (int ks = 0; ks < 8; ++ks) qf[ks] = *(const short8*)(qrow + ks * 16 + hi * 8);
  }

  f32x16 o0 = {0.f,0.f,0.f,0.f,0.f,0.f,0.f,0.f,0.f,0.f,0.f,0.f,0.f,0.f,0.f,0.f};
  f32x16 o1 = o0, o2 = o0, o3 = o0;
  float m_ = -1e30f, lsum = 0.f;
  int ksw = (q32 & 15) << 4;
  int vsw = (q32 & 7) << 4;

  union U8 { short8 s8; unsigned int u[4]; };

#pragma unroll
  for (int i = 0; i < 4; ++i) {
    async16(kbase + koff[i], (char*)Ksm[0] + dst[i]);
    async16(vbase + voff[i], (char*)Vtsm[0] + dst[i]);
  }
  __syncthreads();

  for (int kt = 0; kt < 32; ++kt) {
    int cur = kt & 1;
    if (kt < 31) {
      const char* kt_k = kbase + (size_t)(kt + 1) * (64 * DIM * 2);
      const char* kt_v = vbase + (kt + 1) * 128;
#pragma unroll
      for (int i = 0; i < 4; ++i) {
        async16(kt_k + koff[i], (char*)Ksm[cur ^ 1] + dst[i]);
        async16(kt_v + voff[i], (char*)Vtsm[cur ^ 1] + dst[i]);
      }
    }

    f32x16 st0 = {0.f,0.f,0.f,0.f,0.f,0.f,0.f,0.f,0.f,0.f,0.f,0.f,0.f,0.f,0.f,0.f};
    f32x16 st1 = st0;
    {
      const char* kr0 = (const char*)Ksm[cur] + q32 * 256;
      const char* kr1 = (const char*)Ksm[cur] + (32 + q32) * 256;
      __builtin_amdgcn_s_setprio(1);
#pragma unroll
      for (int ks = 0; ks < 8; ++ks) {
        int cb = (ks * 32 + hi * 16) ^ ksw;
        short8 kf0 = *(const short8*)(kr0 + cb);
        short8 kf1 = *(const short8*)(kr1 + cb);
        st0 = __builtin_amdgcn_mfma_f32_32x32x16_bf16(kf0, qf[ks], st0, 0, 0, 0);
        st1 = __builtin_amdgcn_mfma_f32_32x32x16_bf16(kf1, qf[ks], st1, 0, 0, 0);
      }
      __builtin_amdgcn_s_setprio(0);
    }

    float mx = fmaxf(st0[0], st1[0]);
#pragma unroll
    for (int r = 1; r < 16; ++r) mx = fmaxf(mx, fmaxf(st0[r], st1[r]));
    mx = fmaxf(mx, __shfl_xor(mx, 32));

    if (__any(mx > m_ + 10.0f)) {
      float mn = fmaxf(m_, mx);
      float corr = exp2f(m_ - mn);
      m_ = mn;
      lsum *= corr;
#pragma unroll
      for (int r = 0; r < 16; ++r) {
        float cr = __shfl(corr, (r & 3) + 8 * (r >> 2) + hi4);
        o0[r] *= cr; o1[r] *= cr; o2[r] *= cr; o3[r] *= cr;
      }
    }

#pragma unroll
    for (int r = 0; r < 16; ++r) {
      st0[r] = exp2f(st0[r] - m_);
      st1[r] = exp2f(st1[r] - m_);
    }
    {
      float sm = st0[0] + st1[0];
#pragma unroll
      for (int r = 1; r < 16; ++r) sm += st0[r] + st1[r];
      sm += __shfl_xor(sm, 32);
      lsum += sm;
    }

    U8 pa[4];
#pragma unroll
    for (int b = 0; b < 4; ++b) {
      unsigned int a0, a1, a2, a3;
      if (b < 2) {
        int r0 = (b & 1) * 8;
        a0 = pkbf(st0[r0 + 0], st0[r0 + 1]);
        a1 = pkbf(st0[r0 + 2], st0[r0 + 3]);
        a2 = pkbf(st0[r0 + 4], st0[r0 + 5]);
        a3 = pkbf(st0[r0 + 6], st0[r0 + 7]);
      } else {
        int r0 = (b & 1) * 8;
        a0 = pkbf(st1[r0 + 0], st1[r0 + 1]);
        a1 = pkbf(st1[r0 + 2], st1[r0 + 3]);
        a2 = pkbf(st1[r0 + 4], st1[r0 + 5]);
        a3 = pkbf(st1[r0 + 6], st1[r0 + 7]);
      }
      asm volatile("v_permlane32_swap_b32 %0, %1" : "+v"(a0), "+v"(a2));
      asm volatile("v_permlane32_swap_b32 %0, %1" : "+v"(a1), "+v"(a3));
      pa[b].u[0] = a0; pa[b].u[1] = a1; pa[b].u[2] = a2; pa[b].u[3] = a3;
    }

    __builtin_amdgcn_s_setprio(1);
#pragma unroll
    for (int ks = 0; ks < 4; ++ks) {
      int cb = (ks * 32 + hi * 16) ^ vsw;
      const char* Vp = (const char*)Vtsm[cur];
      short8 vf0 = *(const short8*)(Vp + (0 * 32 + q32) * 128 + cb);
      short8 vf1 = *(const short8*)(Vp + (1 * 32 + q32) * 128 + cb);
      short8 vf2 = *(const short8*)(Vp + (2 * 32 + q32) * 128 + cb);
      short8 vf3 = *(const short8*)(Vp + (3 * 32 + q32) * 128 + cb);
      o0 = __builtin_amdgcn_mfma_f32_32x32x16_bf16(pa[ks].s8, vf0, o0, 0, 0, 0);
      o1 = __builtin_amdgcn_mfma_f32_32x32x16_bf16(pa[ks].s8, vf1, o1, 0, 0, 0);
      o2 = __builtin_amdgcn_mfma_f32_32x32x16_bf16(pa[ks].s8, vf2, o2, 0, 0, 0);
      o3 = __builtin_amdgcn_mfma_f32_32x32x16_bf16(pa[ks].s8, vf3, o3, 0, 0, 0);
    }
    __builtin_amdgcn_s_setprio(0);

    __syncthreads();
  }

  float inv = 1.0f / lsum;
#pragma unroll
  for (int r = 0; r < 16; ++r) {
    float fr = __shfl(inv, (r & 3) + 8 * (r >> 2) + hi4);
    int grow = q0w + (r & 3) + 8 * (r >> 2) + hi4;
    float* orow = out + (size_t)grow * DIM + h * HDIM + q32;
    orow[0]  = o0[r] * fr;
    orow[32] = o1[r] * fr;
    orow[64] = o2[r] * fr;
    orow[96] = o3[r] * fr;
  }
}

extern "C" void kernel_launch(void* const* d_in, const int* in_sizes, int n_in,
                              void* d_out, int out_size, void* d_ws, size_t ws_size,
                              hipStream_t stream) {
  const float* x = (const float*)d_in[0];
  const float* rope_cos = (const float*)d_in[1];
  const float* rope_sin = (const float*)d_in[2];
  const float* Wq = (const float*)d_in[3];
  const float* bq = (const float*)d_in[4];
  const float* Wk = (const float*)d_in[5];
  const float* bk = (const float*)d_in[6];
  const float* Wv = (const float*)d_in[7];
  const float* bv = (const float*)d_in[8];
  const float* gq = (const float*)d_in[9];
  const float* gk = (const float*)d_in[10];
  float* out = (float*)d_out;

  const size_t slab = (size_t)SEQ * DIM;          // bf16 elements
  const size_t wt9elems = (size_t)3 * DIM * DIM;  // fused W^T
  const size_t need = (4 * slab + wt9elems) * 2;  // bytes

  if (ws_size >= need) {
    // fused path: xb | wt9 | qb | kb | vtb
    unsigned short* xb = (unsigned short*)d_ws;
    unsigned short* wt9 = xb + slab;
    unsigned short* qb = wt9 + wt9elems;
    unsigned short* kb = qb + slab;
    unsigned short* vtb = kb + slab;

    k_cvt_x<<<3072, 256, 0, stream>>>(x, xb);
    k_transpose3<<<dim3(DIM / 64, DIM / 64, 3), 256, 0, stream>>>(Wq, Wk, Wv, wt9);
    k_gemm8<<<576, 512, 0, stream>>>(xb, wt9, bq, bk, bv, rope_cos, rope_sin, gq, gk,
                                     qb, kb, vtb);
    k_attn<<<384, 256, 0, stream>>>(qb, kb, vtb, out);
  } else {
    // sequential fallback
    unsigned short* xb = (unsigned short*)d_ws;
    unsigned short* wt = xb + slab;
    unsigned short* qb = wt + (size_t)DIM * DIM;
    unsigned short* kb = qb + slab;
    unsigned short* vtb = kb + slab;

    k_cvt_x<<<3072, 256, 0, stream>>>(x, xb);
    dim3 tg(DIM / 64, DIM / 64);
    k_transpose<<<tg, 256, 0, stream>>>(Wq, wt);
    k_gemm<<<384, 256, 0, stream>>>(xb, wt, bq, qb, 0);
    k_transpose<<<tg, 256, 0, stream>>>(Wk, wt);
    k_gemm<<<384, 256, 0, stream>>>(xb, wt, bk, kb, 0);
    k_transpose<<<tg, 256, 0, stream>>>(Wv, wt);
    k_gemm<<<384, 256, 0, stream>>>(xb, wt, bv, vtb, 1);
    k_normrope<<<SEQ * NHEAD / 4, 256, 0, stream>>>(qb, rope_cos, rope_sin, gq, SCALE_Q);
    k_normrope<<<SEQ * NHEAD / 4, 256, 0, stream>>>(kb, rope_cos, rope_sin, gk, 1.0f);
    k_attn<<<384, 256, 0, stream>>>(qb, kb, vtb, out);
  }
}

// Round 12
// 278.070 us; speedup vs baseline: 1.2919x; 1.2919x over previous
//
#include <hip/hip_runtime.h>
#include <hip/hip_bf16.h>

typedef __attribute__((ext_vector_type(8))) short short8;
typedef __attribute__((ext_vector_type(4))) float f32x4;
typedef __attribute__((ext_vector_type(16))) float f32x16;

#define SEQ 2048
#define DIM 3072
#define NHEAD 24
#define HDIM 128
#define SCALE_Q 0.12751744f  // (1/sqrt(128)) * log2(e)

__device__ __forceinline__ unsigned short f2bf(float f) {
  unsigned int b = __float_as_uint(f);
  b += 0x7fffu + ((b >> 16) & 1u);
  return (unsigned short)(b >> 16);
}
__device__ __forceinline__ float bf2f(unsigned short u) {
  return __uint_as_float(((unsigned int)u) << 16);
}
__device__ __forceinline__ unsigned int pkbf(float a, float b) {
  __hip_bfloat162 h = __float22bfloat162_rn(make_float2(a, b));
  return *(unsigned int*)&h;
}

__device__ __forceinline__ void async16(const void* g, void* l) {
  __builtin_amdgcn_global_load_lds(
      (const __attribute__((address_space(1))) unsigned int*)g,
      (__attribute__((address_space(3))) unsigned int*)l, 16, 0, 0);
}

// ---------------- cast x (fp32 -> bf16), grid-stride, 8 elems/thread ----------------
__device__ __forceinline__ void cvt_x_body(const float* __restrict__ x,
                                           unsigned short* __restrict__ xb, int bid,
                                           int nblocks) {
  const int total = SEQ * DIM;
  for (int idx = (bid * 256 + threadIdx.x) * 8; idx < total; idx += nblocks * 256 * 8) {
    float4 a = *(const float4*)(x + idx);
    float4 b = *(const float4*)(x + idx + 4);
    short8 o;
    o[0] = (short)f2bf(a.x); o[1] = (short)f2bf(a.y);
    o[2] = (short)f2bf(a.z); o[3] = (short)f2bf(a.w);
    o[4] = (short)f2bf(b.x); o[5] = (short)f2bf(b.y);
    o[6] = (short)f2bf(b.z); o[7] = (short)f2bf(b.w);
    *(short8*)(xb + idx) = o;
  }
}

__global__ void k_cvt_x(const float* __restrict__ x, unsigned short* __restrict__ xb) {
  cvt_x_body(x, xb, blockIdx.x, gridDim.x);
}

// ---------------- transpose + cast one W (K x N fp32) -> Wt rows (N x K bf16) ----------------
__device__ __forceinline__ void transpose_tile(const float* __restrict__ w,
                                               unsigned short* __restrict__ wt,
                                               int n0, int k0, int outRowBase, int t) {
  __shared__ unsigned short tile[64][68];
  int c4 = (t & 15) * 4;
  int r0 = t >> 4;
#pragma unroll
  for (int j = 0; j < 4; ++j) {
    int r = r0 + 16 * j;
    float4 v = *(const float4*)(w + (size_t)(k0 + r) * DIM + n0 + c4);
    ushort4 u;
    u.x = f2bf(v.x); u.y = f2bf(v.y); u.z = f2bf(v.z); u.w = f2bf(v.w);
    *(ushort4*)&tile[r][c4] = u;
  }
  __syncthreads();
#pragma unroll
  for (int j = 0; j < 4; ++j) {
    int nn = r0 + 16 * j;
    ushort4 u;
    u.x = tile[c4 + 0][nn]; u.y = tile[c4 + 1][nn];
    u.z = tile[c4 + 2][nn]; u.w = tile[c4 + 3][nn];
    *(ushort4*)(wt + (size_t)(outRowBase + n0 + nn) * DIM + k0 + c4) = u;
  }
}

__global__ __launch_bounds__(256) void k_transpose(const float* __restrict__ w,
                                                   unsigned short* __restrict__ wt) {
  transpose_tile(w, wt, blockIdx.x * 64, blockIdx.y * 64, 0, threadIdx.x);
}

// z<3: transpose Wq/Wk/Wv into wt9. z==3: cast x -> xb (grid-stride over 48x48 blocks).
__global__ __launch_bounds__(256) void k_prep(const float* __restrict__ w0,
                                              const float* __restrict__ w1,
                                              const float* __restrict__ w2,
                                              unsigned short* __restrict__ wt,
                                              const float* __restrict__ x,
                                              unsigned short* __restrict__ xb) {
  if (blockIdx.z == 3) {
    cvt_x_body(x, xb, blockIdx.y * gridDim.x + blockIdx.x, gridDim.x * gridDim.y);
    return;
  }
  const float* w = blockIdx.z == 0 ? w0 : (blockIdx.z == 1 ? w1 : w2);
  transpose_tile(w, wt, blockIdx.x * 64, blockIdx.y * 64, blockIdx.z * DIM, threadIdx.x);
}

// ---------------- GEMM core: one 128x128 tile, BK=64, T2 swizzle ----------------
__device__ __forceinline__ void gemm_tile(const unsigned short* __restrict__ xb,
                                          const unsigned short* __restrict__ wt,
                                          int bm, int bn, int t, f32x4 (&acc)[4][4],
                                          unsigned short* As, unsigned short* Bs) {
  int l = t & 63, w = t >> 6;
  int wr = w >> 1, wc = w & 1;
  int lr = l & 15, kc = l >> 4;
  const char* aB = (const char*)xb;
  const char* bB = (const char*)wt;
  char* asmB = (char*)As;
  char* bsmB = (char*)Bs;
  int sw = (lr & 7) << 4;

  for (int k0 = 0; k0 < DIM; k0 += 64) {
#pragma unroll
    for (int i = 0; i < 4; ++i) {
      int off = (t + 256 * i) * 16;
      int row = off >> 7;
      int cb = off & 127;
      int scb = cb ^ ((row & 7) << 4);
      async16(aB + ((size_t)(bm * 128 + row) * DIM + k0) * 2 + scb, asmB + off);
      async16(bB + ((size_t)(bn * 128 + row) * DIM + k0) * 2 + scb, bsmB + off);
    }
    __syncthreads();
#pragma unroll
    for (int kk = 0; kk < 2; ++kk) {
      short8 af[4], bf[4];
#pragma unroll
      for (int m = 0; m < 4; ++m)
        af[m] = *(const short8*)(asmB + (wr * 64 + m * 16 + lr) * 128 +
                                 ((kk * 64 + kc * 16) ^ sw));
#pragma unroll
      for (int n = 0; n < 4; ++n)
        bf[n] = *(const short8*)(bsmB + (wc * 64 + n * 16 + lr) * 128 +
                                 ((kk * 64 + kc * 16) ^ sw));
#pragma unroll
      for (int m = 0; m < 4; ++m)
#pragma unroll
        for (int n = 0; n < 4; ++n)
          acc[m][n] = __builtin_amdgcn_mfma_f32_16x16x32_bf16(af[m], bf[n], acc[m][n], 0, 0, 0);
    }
    __syncthreads();
  }
}

// ---------------- fallback GEMM (one W at a time) ----------------
__global__ __launch_bounds__(256) void k_gemm(const unsigned short* __restrict__ xb,
                                              const unsigned short* __restrict__ wt,
                                              const float* __restrict__ bias,
                                              unsigned short* __restrict__ out,
                                              int vmode) {
  __shared__ unsigned short As[128 * 64];
  __shared__ unsigned short Bs[128 * 64];
  int t = threadIdx.x;
  int fid = blockIdx.x;
  int logical = (fid & 7) * 48 + (fid >> 3);
  int bm = logical & 15, bn = logical >> 4;

  f32x4 acc[4][4];
#pragma unroll
  for (int m = 0; m < 4; ++m)
#pragma unroll
    for (int n = 0; n < 4; ++n) acc[m][n] = (f32x4){0.f, 0.f, 0.f, 0.f};

  gemm_tile(xb, wt, bm, bn, t, acc, As, Bs);

  int l = t & 63, w = t >> 6;
  int wr = w >> 1, wc = w & 1;
  int lr = l & 15, lq = l >> 4;
  if (vmode) {
#pragma unroll
    for (int m = 0; m < 4; ++m)
#pragma unroll
      for (int n = 0; n < 4; ++n) {
        int gcol = bn * 128 + wc * 64 + n * 16 + lr;
        float bv = bias[gcol];
        int grow = bm * 128 + wr * 64 + m * 16 + lq * 4;
        ushort4 u;
        u.x = f2bf(acc[m][n][0] + bv);
        u.y = f2bf(acc[m][n][1] + bv);
        u.z = f2bf(acc[m][n][2] + bv);
        u.w = f2bf(acc[m][n][3] + bv);
        *(ushort4*)(out + (size_t)gcol * SEQ + grow) = u;
      }
  } else {
#pragma unroll
    for (int m = 0; m < 4; ++m)
#pragma unroll
      for (int n = 0; n < 4; ++n) {
        int gcol = bn * 128 + wc * 64 + n * 16 + lr;
        float bv = bias[gcol];
#pragma unroll
        for (int i = 0; i < 4; ++i) {
          int grow = bm * 128 + wr * 64 + m * 16 + lq * 4 + i;
          out[(size_t)grow * DIM + gcol] = f2bf(acc[m][n][i] + bv);
        }
      }
  }
}

// ---------------- fused GEMM + RMSNorm + RoPE epilogue (round-7/10 config, known-good) ----
__global__ __launch_bounds__(256, 4) void k_gemm3(
    const unsigned short* __restrict__ xb, const unsigned short* __restrict__ wt,
    const float* __restrict__ bq, const float* __restrict__ bk,
    const float* __restrict__ bv, const float* __restrict__ rope_cos,
    const float* __restrict__ rope_sin, const float* __restrict__ gq,
    const float* __restrict__ gk, unsigned short* __restrict__ qb,
    unsigned short* __restrict__ kb, unsigned short* __restrict__ vtb) {
  __shared__ unsigned short As[128 * 64];
  __shared__ unsigned short Bs[128 * 64];
  __shared__ float ssum[2][128];
  int t = threadIdx.x;
  int fid = blockIdx.x;
  // bijective 1152 = 8 xcd * (4 chunks * 9 bn * 4 bmi)
  int xcd = fid & 7, li = fid >> 3;
  int c = li / 36, r = li % 36;
  int bnl9 = r >> 2, bmi = r & 3;
  int bm = c * 4 + bmi;        // 0..15
  int bn = xcd * 9 + bnl9;     // 0..71

  f32x4 acc[4][4];
#pragma unroll
  for (int m = 0; m < 4; ++m)
#pragma unroll
    for (int n = 0; n < 4; ++n) acc[m][n] = (f32x4){0.f, 0.f, 0.f, 0.f};

  gemm_tile(xb, wt, bm, bn, t, acc, As, Bs);

  int l = t & 63, w = t >> 6;
  int wr = w >> 1, wc = w & 1;
  int lr = l & 15, lq = l >> 4;

  int region = bn >= 48 ? 2 : (bn >= 24 ? 1 : 0);
  int bnl = bn - region * 24;
  const float* bias = region == 0 ? bq : (region == 1 ? bk : bv);

  if (region == 2) {  // V: transposed write into vtb[d_global][s]
#pragma unroll
    for (int m = 0; m < 4; ++m)
#pragma unroll
      for (int n = 0; n < 4; ++n) {
        int gcol = bnl * 128 + wc * 64 + n * 16 + lr;
        float bv_ = bias[gcol];
        int grow = bm * 128 + wr * 64 + m * 16 + lq * 4;
        ushort4 u;
        u.x = f2bf(acc[m][n][0] + bv_);
        u.y = f2bf(acc[m][n][1] + bv_);
        u.z = f2bf(acc[m][n][2] + bv_);
        u.w = f2bf(acc[m][n][3] + bv_);
        *(ushort4*)(vtb + (size_t)gcol * SEQ + grow) = u;
      }
  } else {  // q/k: fused bias + RMSNorm + RoPE
    unsigned short* outp = region == 0 ? qb : kb;
    const float* g = region == 0 ? gq : gk;
    float scale = region == 0 ? SCALE_Q : 1.0f;

    float gv[4], bvv[4];
#pragma unroll
    for (int n = 0; n < 4; ++n) {
      int cl = wc * 64 + n * 16 + lr;
      gv[n] = g[cl];
      bvv[n] = bias[bnl * 128 + cl];
    }
#pragma unroll
    for (int m = 0; m < 4; ++m)
#pragma unroll
      for (int n = 0; n < 4; ++n)
#pragma unroll
        for (int i = 0; i < 4; ++i) acc[m][n][i] += bvv[n];

#pragma unroll
    for (int m = 0; m < 4; ++m)
#pragma unroll
      for (int i = 0; i < 4; ++i) {
        float ss = acc[m][0][i] * acc[m][0][i] + acc[m][1][i] * acc[m][1][i] +
                   acc[m][2][i] * acc[m][2][i] + acc[m][3][i] * acc[m][3][i];
        ss += __shfl_xor(ss, 1);
        ss += __shfl_xor(ss, 2);
        ss += __shfl_xor(ss, 4);
        ss += __shfl_xor(ss, 8);
        if (lr == m * 4 + i) ssum[wc][wr * 64 + m * 16 + lq * 4 + i] = ss;
      }
    __syncthreads();

#pragma unroll
    for (int m = 0; m < 4; ++m)
#pragma unroll
      for (int i = 0; i < 4; ++i) {
        int rl = wr * 64 + m * 16 + lq * 4 + i;
        float rn = rsqrtf((ssum[0][rl] + ssum[1][rl]) * (1.0f / 128.0f) + 1e-6f);
        int s_idx = bm * 128 + rl;
        const float* cr = rope_cos + (size_t)s_idx * HDIM;
        const float* sr = rope_sin + (size_t)s_idx * HDIM;
        unsigned short* orow = outp + (size_t)s_idx * DIM + bnl * 128;
#pragma unroll
        for (int n = 0; n < 4; ++n) {
          int cl = wc * 64 + n * 16 + lr;
          float xn = acc[m][n][i] * rn * gv[n];
          float pr = __shfl_xor(xn, 1);
          float cv = cr[cl], sv = sr[cl];
          float o = (lr & 1) ? fmaf(xn, cv, pr * sv) : fmaf(xn, cv, -pr * sv);
          orow[cl] = f2bf(o * scale);
        }
      }
  }
}

// ---------------- RMSNorm + RoPE (fallback path only) ----------------
__global__ void k_normrope(unsigned short* __restrict__ qk, const float* __restrict__ cosb,
                           const float* __restrict__ sinb, const float* __restrict__ g,
                           float scale) {
  int t = threadIdx.x;
  int w = t >> 6, l = t & 63;
  int row = blockIdx.x * 4 + w;
  int s_idx = row / NHEAD, head = row % NHEAD;
  size_t base = (size_t)s_idx * DIM + head * HDIM;
  unsigned int pair = *(const unsigned int*)(qk + base + 2 * l);
  float x0 = bf2f((unsigned short)(pair & 0xffffu));
  float x1 = bf2f((unsigned short)(pair >> 16));
  float ss = x0 * x0 + x1 * x1;
#pragma unroll
  for (int off = 1; off < 64; off <<= 1) ss += __shfl_xor(ss, off);
  float r = rsqrtf(ss * (1.0f / 128.0f) + 1e-6f);
  float g0 = g[2 * l], g1 = g[2 * l + 1];
  float c0 = cosb[s_idx * HDIM + 2 * l], c1 = cosb[s_idx * HDIM + 2 * l + 1];
  float s0 = sinb[s_idx * HDIM + 2 * l], s1 = sinb[s_idx * HDIM + 2 * l + 1];
  float xn0 = x0 * r * g0, xn1 = x1 * r * g1;
  float o0 = (xn0 * c0 - xn1 * s0) * scale;
  float o1 = (xn1 * c1 + xn0 * s1) * scale;
  unsigned int po = (unsigned int)f2bf(o0) | ((unsigned int)f2bf(o1) << 16);
  *(unsigned int*)(qk + base + 2 * l) = po;
}

// ---------------- Flash attention: 4 waves x 32 q-rows, 2-phase dbuf (round-10) ----
__global__ __launch_bounds__(256, 2) void k_attn(const unsigned short* __restrict__ q,
                                                 const unsigned short* __restrict__ k,
                                                 const unsigned short* __restrict__ vt,
                                                 float* __restrict__ out) {
  __shared__ unsigned short Ksm[2][64 * 128];
  __shared__ unsigned short Vtsm[2][128 * 64];
  int t = threadIdx.x;
  int w = t >> 6, l = t & 63;
  int q32 = l & 31, hi = l >> 5;
  int hi4 = hi * 4;
  int fid = blockIdx.x;
  int logical = (fid & 7) * 48 + (fid >> 3);  // bijective: 384 = 8*48
  int qt = logical & 15, h = logical >> 4;
  int q0w = qt * 128 + w * 32;

  const char* kbase = (const char*)k + (size_t)h * HDIM * 2;
  const char* vbase = (const char*)vt + (size_t)h * HDIM * SEQ * 2;

  int koff[4], voff[4], dst[4];
#pragma unroll
  for (int i = 0; i < 4; ++i) {
    int off = (t + 256 * i) * 16;
    dst[i] = off;
    int krow = off >> 8, kcb = off & 255;
    koff[i] = krow * (DIM * 2) + (kcb ^ ((krow & 15) << 4));
    int vrow = off >> 7, vcb = off & 127;
    voff[i] = vrow * (SEQ * 2) + (vcb ^ ((vrow & 7) << 4));
  }

  short8 qf[8];
  {
    const unsigned short* qrow = q + (size_t)(q0w + q32) * DIM + h * HDIM;
#pragma unroll
    for (int ks = 0; ks < 8; ++ks) qf[ks] = *(const short8*)(qrow + ks * 16 + hi * 8);
  }

  f32x16 o0 = {0.f,0.f,0.f,0.f,0.f,0.f,0.f,0.f,0.f,0.f,0.f,0.f,0.f,0.f,0.f,0.f};
  f32x16 o1 = o0, o2 = o0, o3 = o0;
  float m_ = -1e30f, lsum = 0.f;
  int ksw = (q32 & 15) << 4;
  int vsw = (q32 & 7) << 4;

  union U8 { short8 s8; unsigned int u[4]; };

#pragma unroll
  for (int i = 0; i < 4; ++i) {
    async16(kbase + koff[i], (char*)Ksm[0] + dst[i]);
    async16(vbase + voff[i], (char*)Vtsm[0] + dst[i]);
  }
  __syncthreads();

  for (int kt = 0; kt < 32; ++kt) {
    int cur = kt & 1;
    if (kt < 31) {
      const char* kt_k = kbase + (size_t)(kt + 1) * (64 * DIM * 2);
      const char* kt_v = vbase + (kt + 1) * 128;
#pragma unroll
      for (int i = 0; i < 4; ++i) {
        async16(kt_k + koff[i], (char*)Ksm[cur ^ 1] + dst[i]);
        async16(kt_v + voff[i], (char*)Vtsm[cur ^ 1] + dst[i]);
      }
    }

    f32x16 st0 = {0.f,0.f,0.f,0.f,0.f,0.f,0.f,0.f,0.f,0.f,0.f,0.f,0.f,0.f,0.f,0.f};
    f32x16 st1 = st0;
    {
      const char* kr0 = (const char*)Ksm[cur] + q32 * 256;
      const char* kr1 = (const char*)Ksm[cur] + (32 + q32) * 256;
      __builtin_amdgcn_s_setprio(1);
#pragma unroll
      for (int ks = 0; ks < 8; ++ks) {
        int cb = (ks * 32 + hi * 16) ^ ksw;
        short8 kf0 = *(const short8*)(kr0 + cb);
        short8 kf1 = *(const short8*)(kr1 + cb);
        st0 = __builtin_amdgcn_mfma_f32_32x32x16_bf16(kf0, qf[ks], st0, 0, 0, 0);
        st1 = __builtin_amdgcn_mfma_f32_32x32x16_bf16(kf1, qf[ks], st1, 0, 0, 0);
      }
      __builtin_amdgcn_s_setprio(0);
    }

    float mx = fmaxf(st0[0], st1[0]);
#pragma unroll
    for (int r = 1; r < 16; ++r) mx = fmaxf(mx, fmaxf(st0[r], st1[r]));
    mx = fmaxf(mx, __shfl_xor(mx, 32));

    if (__any(mx > m_ + 10.0f)) {
      float mn = fmaxf(m_, mx);
      float corr = exp2f(m_ - mn);
      m_ = mn;
      lsum *= corr;
#pragma unroll
      for (int r = 0; r < 16; ++r) {
        float cr = __shfl(corr, (r & 3) + 8 * (r >> 2) + hi4);
        o0[r] *= cr; o1[r] *= cr; o2[r] *= cr; o3[r] *= cr;
      }
    }

#pragma unroll
    for (int r = 0; r < 16; ++r) {
      st0[r] = exp2f(st0[r] - m_);
      st1[r] = exp2f(st1[r] - m_);
    }
    {
      float sm = st0[0] + st1[0];
#pragma unroll
      for (int r = 1; r < 16; ++r) sm += st0[r] + st1[r];
      sm += __shfl_xor(sm, 32);
      lsum += sm;
    }

    U8 pa[4];
#pragma unroll
    for (int b = 0; b < 4; ++b) {
      unsigned int a0, a1, a2, a3;
      if (b < 2) {
        int r0 = (b & 1) * 8;
        a0 = pkbf(st0[r0 + 0], st0[r0 + 1]);
        a1 = pkbf(st0[r0 + 2], st0[r0 + 3]);
        a2 = pkbf(st0[r0 + 4], st0[r0 + 5]);
        a3 = pkbf(st0[r0 + 6], st0[r0 + 7]);
      } else {
        int r0 = (b & 1) * 8;
        a0 = pkbf(st1[r0 + 0], st1[r0 + 1]);
        a1 = pkbf(st1[r0 + 2], st1[r0 + 3]);
        a2 = pkbf(st1[r0 + 4], st1[r0 + 5]);
        a3 = pkbf(st1[r0 + 6], st1[r0 + 7]);
      }
      asm volatile("v_permlane32_swap_b32 %0, %1" : "+v"(a0), "+v"(a2));
      asm volatile("v_permlane32_swap_b32 %0, %1" : "+v"(a1), "+v"(a3));
      pa[b].u[0] = a0; pa[b].u[1] = a1; pa[b].u[2] = a2; pa[b].u[3] = a3;
    }

    __builtin_amdgcn_s_setprio(1);
#pragma unroll
    for (int ks = 0; ks < 4; ++ks) {
      int cb = (ks * 32 + hi * 16) ^ vsw;
      const char* Vp = (const char*)Vtsm[cur];
      short8 vf0 = *(const short8*)(Vp + (0 * 32 + q32) * 128 + cb);
      short8 vf1 = *(const short8*)(Vp + (1 * 32 + q32) * 128 + cb);
      short8 vf2 = *(const short8*)(Vp + (2 * 32 + q32) * 128 + cb);
      short8 vf3 = *(const short8*)(Vp + (3 * 32 + q32) * 128 + cb);
      o0 = __builtin_amdgcn_mfma_f32_32x32x16_bf16(pa[ks].s8, vf0, o0, 0, 0, 0);
      o1 = __builtin_amdgcn_mfma_f32_32x32x16_bf16(pa[ks].s8, vf1, o1, 0, 0, 0);
      o2 = __builtin_amdgcn_mfma_f32_32x32x16_bf16(pa[ks].s8, vf2, o2, 0, 0, 0);
      o3 = __builtin_amdgcn_mfma_f32_32x32x16_bf16(pa[ks].s8, vf3, o3, 0, 0, 0);
    }
    __builtin_amdgcn_s_setprio(0);

    __syncthreads();
  }

  float inv = 1.0f / lsum;
#pragma unroll
  for (int r = 0; r < 16; ++r) {
    float fr = __shfl(inv, (r & 3) + 8 * (r >> 2) + hi4);
    int grow = q0w + (r & 3) + 8 * (r >> 2) + hi4;
    float* orow = out + (size_t)grow * DIM + h * HDIM + q32;
    orow[0]  = o0[r] * fr;
    orow[32] = o1[r] * fr;
    orow[64] = o2[r] * fr;
    orow[96] = o3[r] * fr;
  }
}

extern "C" void kernel_launch(void* const* d_in, const int* in_sizes, int n_in,
                              void* d_out, int out_size, void* d_ws, size_t ws_size,
                              hipStream_t stream) {
  const float* x = (const float*)d_in[0];
  const float* rope_cos = (const float*)d_in[1];
  const float* rope_sin = (const float*)d_in[2];
  const float* Wq = (const float*)d_in[3];
  const float* bq = (const float*)d_in[4];
  const float* Wk = (const float*)d_in[5];
  const float* bk = (const float*)d_in[6];
  const float* Wv = (const float*)d_in[7];
  const float* bv = (const float*)d_in[8];
  const float* gq = (const float*)d_in[9];
  const float* gk = (const float*)d_in[10];
  float* out = (float*)d_out;

  const size_t slab = (size_t)SEQ * DIM;          // bf16 elements
  const size_t wt9elems = (size_t)3 * DIM * DIM;  // fused W^T
  const size_t need = (4 * slab + wt9elems) * 2;  // bytes

  if (ws_size >= need) {
    // fused path: xb | wt9 | qb | kb | vtb
    unsigned short* xb = (unsigned short*)d_ws;
    unsigned short* wt9 = xb + slab;
    unsigned short* qb = wt9 + wt9elems;
    unsigned short* kb = qb + slab;
    unsigned short* vtb = kb + slab;

    k_prep<<<dim3(DIM / 64, DIM / 64, 4), 256, 0, stream>>>(Wq, Wk, Wv, wt9, x, xb);
    k_gemm3<<<1152, 256, 0, stream>>>(xb, wt9, bq, bk, bv, rope_cos, rope_sin, gq, gk,
                                      qb, kb, vtb);
    k_attn<<<384, 256, 0, stream>>>(qb, kb, vtb, out);
  } else {
    // sequential fallback
    unsigned short* xb = (unsigned short*)d_ws;
    unsigned short* wt = xb + slab;
    unsigned short* qb = wt + (size_t)DIM * DIM;
    unsigned short* kb = qb + slab;
    unsigned short* vtb = kb + slab;

    k_cvt_x<<<3072, 256, 0, stream>>>(x, xb);
    dim3 tg(DIM / 64, DIM / 64);
    k_transpose<<<tg, 256, 0, stream>>>(Wq, wt);
    k_gemm<<<384, 256, 0, stream>>>(xb, wt, bq, qb, 0);
    k_transpose<<<tg, 256, 0, stream>>>(Wk, wt);
    k_gemm<<<384, 256, 0, stream>>>(xb, wt, bk, kb, 0);
    k_transpose<<<tg, 256, 0, stream>>>(Wv, wt);
    k_gemm<<<384, 256, 0, stream>>>(xb, wt, bv, vtb, 1);
    k_normrope<<<SEQ * NHEAD / 4, 256, 0, stream>>>(qb, rope_cos, rope_sin, gq, SCALE_Q);
    k_normrope<<<SEQ * NHEAD / 4, 256, 0, stream>>>(kb, rope_cos, rope_sin, gk, 1.0f);
    k_attn<<<384, 256, 0, stream>>>(qb, kb, vtb, out);
  }
}